// Round 12
// baseline (69.892 us; speedup 1.0000x reference)
//
#include <hip/hip_runtime.h>
#include <hip/hip_cooperative_groups.h>
#include <cmath>

namespace cg = cooperative_groups;

#define HW   262144          // 512*512
#define NC   16
#define NB   8
#define NSEG 16
#define SEGSZ (HW / NSEG)    // 16384
#define NBLK 1024            // cooperative grid: 4 blocks/CU on 256 CUs
#define BPB  (NBLK / NB)     // 128 blocks per batch (coop)
#define PXB  (HW / BPB)      // 2048 px per block (coop)
#define EPS  1e-5f

typedef float f32x4 __attribute__((ext_vector_type(4)));
typedef float f32x2 __attribute__((ext_vector_type(2)));
typedef short bf16x8 __attribute__((ext_vector_type(8)));

// sigmoid(tanh(x)): tanh via fast exp+rcp, sigmoid via odd Taylor on [-1,1]
__device__ __forceinline__ float gsig(float x) {
    float E = __expf(2.0f * x);
    float t = 1.0f - 2.0f * __builtin_amdgcn_rcpf(E + 1.0f);   // tanh(x)
    float t2 = t * t;
    return fmaf(t, fmaf(t2, fmaf(t2, 0.0020833333f, -0.0208333333f), 0.25f), 0.5f);
}

static __device__ __forceinline__ bf16x8 mk8(unsigned a, unsigned b,
                                             unsigned c, unsigned d) {
    union { unsigned u[4]; bf16x8 v; } r;
    r.u[0] = a; r.u[1] = b; r.u[2] = c; r.u[3] = d;
    return r.v;
}
static __device__ __forceinline__ unsigned pkhi(float x0, float x1) {
    return (__float_as_uint(x0) >> 16) | (__float_as_uint(x1) & 0xFFFF0000u);
}
static __device__ __forceinline__ float trunc_bf(float x) {
    return __uint_as_float(__float_as_uint(x) & 0xFFFF0000u);
}

// one 16ch x 16px MFMA tile (split-bf16 for A and W4 paths)
static __device__ __forceinline__ f32x4 tile16(float x0, float x1, float x2, float x3,
                                               bf16x8 Af, bf16x8 Gf, bf16x8 Wf,
                                               f32x4 biasA, f32x4 biasG, f32x4 biasW) {
    unsigned vh01 = pkhi(x0, x1), vh23 = pkhi(x2, x3);
    unsigned vl01 = pkhi(x0 - trunc_bf(x0), x1 - trunc_bf(x1));
    unsigned vl23 = pkhi(x2 - trunc_bf(x2), x3 - trunc_bf(x3));
    bf16x8 B1 = mk8(vh01, vh23, vl01, vl23);   // [vh ; vl]
    bf16x8 B2 = mk8(vl01, vl23, vh01, vh23);   // [vl ; vh]
    f32x4 wh = __builtin_amdgcn_mfma_f32_16x16x32_bf16(Af, B1, biasA, 0, 0, 0);
    wh = __builtin_amdgcn_mfma_f32_16x16x32_bf16(Af, B2, wh, 0, 0, 0);
    f32x4 gr = __builtin_amdgcn_mfma_f32_16x16x32_bf16(Gf, B1, biasG, 0, 0, 0);
    float u0 = fmaf(x0, gsig(wh[0]) + gsig(gr[0]), x0);
    float u1 = fmaf(x1, gsig(wh[1]) + gsig(gr[1]), x1);
    float u2 = fmaf(x2, gsig(wh[2]) + gsig(gr[2]), x2);
    float u3 = fmaf(x3, gsig(wh[3]) + gsig(gr[3]), x3);
    unsigned uh01 = pkhi(u0, u1), uh23 = pkhi(u2, u3);
    unsigned ul01 = pkhi(u0 - trunc_bf(u0), u1 - trunc_bf(u1));
    unsigned ul23 = pkhi(u2 - trunc_bf(u2), u3 - trunc_bf(u3));
    f32x4 o = __builtin_amdgcn_mfma_f32_16x16x32_bf16(Wf, mk8(uh01, uh23, ul01, ul23), biasW, 0, 0, 0);
    o = __builtin_amdgcn_mfma_f32_16x16x32_bf16(Wf, mk8(ul01, ul23, uh01, uh23), o, 0, 0, 0);
    return o;
}

// main MFMA loop over NITER f32x2-steps of 16 (per wave slice)
template<int NITER>
static __device__ __forceinline__ void phase3(const f32x2* __restrict__ xb2,
                                              f32x2* __restrict__ ob2,
                                              unsigned basep, int kg,
                                              bf16x8 Af, bf16x8 Gf, bf16x8 Wf,
                                              f32x4 biasA, f32x4 biasG, f32x4 biasW) {
    unsigned off0 = (unsigned)(kg * 4 + 0) * (HW / 2) + basep;
    unsigned off1 = (unsigned)(kg * 4 + 1) * (HW / 2) + basep;
    unsigned off2 = (unsigned)(kg * 4 + 2) * (HW / 2) + basep;
    unsigned off3 = (unsigned)(kg * 4 + 3) * (HW / 2) + basep;
    #pragma unroll
    for (int it = 0; it < NITER; ++it) {
        f32x2 v0 = xb2[off0 + it * 16];
        f32x2 v1 = xb2[off1 + it * 16];
        f32x2 v2 = xb2[off2 + it * 16];
        f32x2 v3 = xb2[off3 + it * 16];
        f32x4 oA = tile16(v0.x, v1.x, v2.x, v3.x, Af, Gf, Wf, biasA, biasG, biasW);
        f32x4 oB = tile16(v0.y, v1.y, v2.y, v3.y, Af, Gf, Wf, biasA, biasG, biasW);
        f32x2 s0; s0.x = oA[0]; s0.y = oB[0];
        f32x2 s1; s1.x = oA[1]; s1.y = oB[1];
        f32x2 s2; s2.x = oA[2]; s2.y = oB[2];
        f32x2 s3; s3.x = oA[3]; s3.y = oB[3];
        __builtin_nontemporal_store(s0, &ob2[off0 + it * 16]);
        __builtin_nontemporal_store(s1, &ob2[off1 + it * 16]);
        __builtin_nontemporal_store(s2, &ob2[off2 + it * 16]);
        __builtin_nontemporal_store(s3, &ob2[off3 + it * 16]);
    }
}

// ---------------- fallback pass 1: per-(b,c,seg) partial sum & max ----------------
__global__ __launch_bounds__(256) void k_reduce(const float* __restrict__ x,
                                                float* __restrict__ psum,
                                                float* __restrict__ pmax) {
    int plane = blockIdx.x / NSEG;
    int seg   = blockIdx.x - plane * NSEG;
    const float4* p = reinterpret_cast<const float4*>(
        x + (size_t)plane * HW + (size_t)seg * SEGSZ);
    int t = threadIdx.x;
    float s = 0.0f, m = -INFINITY;
    #pragma unroll
    for (int it = 0; it < SEGSZ / (256 * 4); ++it) {
        float4 v = p[it * 256 + t];
        s += (v.x + v.y) + (v.z + v.w);
        m = fmaxf(m, fmaxf(fmaxf(v.x, v.y), fmaxf(v.z, v.w)));
    }
    #pragma unroll
    for (int off = 32; off > 0; off >>= 1) {
        s += __shfl_down(s, off, 64);
        m = fmaxf(m, __shfl_down(m, off, 64));
    }
    __shared__ float ls[4], lm[4];
    int wid = t >> 6, lane = t & 63;
    if (lane == 0) { ls[wid] = s; lm[wid] = m; }
    __syncthreads();
    if (t == 0) {
        psum[blockIdx.x] = (ls[0] + ls[1]) + (ls[2] + ls[3]);
        pmax[blockIdx.x] = fmaxf(fmaxf(lm[0], lm[1]), fmaxf(lm[2], lm[3]));
    }
}

// ---------------- fallback pass 2: fold params in-block + MFMA main ----------------
__global__ __launch_bounds__(256) void k_main2(
    const float* __restrict__ x,
    const float* __restrict__ psum, const float* __restrict__ pmax,
    const float* __restrict__ Wc, const float* __restrict__ bc,
    const float* __restrict__ W1, const float* __restrict__ b1,
    const float* __restrict__ W2, const float* __restrict__ b2,
    const float* __restrict__ W3, const float* __restrict__ b3,
    const float* __restrict__ W4, const float* __restrict__ b4,
    float* __restrict__ out)
{
    int bid = blockIdx.x;
    int b   = bid >> 8;
    int t   = threadIdx.x;
    int wave = t >> 6, lane = t & 63;

    __shared__ float r2s[NC], r4s[NC];
    __shared__ float sA[NC][17], sG[NC][17], sbias[48];

    if (t < NC) {
        const float* src = psum + (b * NC + t) * NSEG;
        float s = 0.0f;
        #pragma unroll
        for (int k = 0; k < NSEG; ++k) s += src[k];
        r2s[t] = 1.0f / (s * (1.0f / (float)HW) + EPS);
    } else if (t < 2 * NC) {
        int c = t - NC;
        const float* src = pmax + (b * NC + c) * NSEG;
        float m = -INFINITY;
        #pragma unroll
        for (int k = 0; k < NSEG; ++k) m = fmaxf(m, src[k]);
        r4s[c] = 1.0f / (m + EPS);
    }
    __syncthreads();
    {
        int o = t >> 4, i = t & 15;
        float a = 0.0f, g = 0.0f;
        #pragma unroll
        for (int c = 0; c < NC; ++c) {
            a = fmaf(W2[o * 16 + c] * r2s[c], Wc[c * 16 + i], a);
            g = fmaf(W3[o * 16 + c] * r4s[c], W1[c * 16 + i], g);
        }
        sA[o][i] = a; sG[o][i] = g;
        if (t < NC) {
            float ba = 0.0f;
            #pragma unroll
            for (int c = 0; c < NC; ++c) ba = fmaf(W2[t * 16 + c] * r2s[c], bc[c], ba);
            sbias[t] = ba + b2[t];
        } else if (t < 2 * NC) {
            int o2 = t - NC; float bg = 0.0f;
            #pragma unroll
            for (int c = 0; c < NC; ++c) bg = fmaf(W3[o2 * 16 + c] * r4s[c], b1[c], bg);
            sbias[NC + o2] = bg + b3[o2];
        } else if (t < 3 * NC) {
            sbias[t] = b4[t - 2 * NC];
        }
    }
    __syncthreads();

    int m_ = lane & 15, kg = lane >> 4;
    f32x4 wa, wg, w4v, biasA, biasG, biasW;
    #pragma unroll
    for (int r = 0; r < 4; ++r) {
        wa[r]    = sA[m_][kg * 4 + r];
        wg[r]    = sG[m_][kg * 4 + r];
        w4v[r]   = W4[m_ * 16 + kg * 4 + r];
        biasA[r] = sbias[kg * 4 + r];
        biasG[r] = sbias[16 + kg * 4 + r];
        biasW[r] = sbias[32 + kg * 4 + r];
    }
    unsigned ah01 = pkhi(wa[0], wa[1]), ah23 = pkhi(wa[2], wa[3]);
    unsigned al01 = pkhi(wa[0] - trunc_bf(wa[0]), wa[1] - trunc_bf(wa[1]));
    unsigned al23 = pkhi(wa[2] - trunc_bf(wa[2]), wa[3] - trunc_bf(wa[3]));
    bf16x8 Af = mk8(ah01, ah23, al01, al23);
    unsigned g01 = pkhi(wg[0], wg[1]), g23 = pkhi(wg[2], wg[3]);
    bf16x8 Gf = mk8(g01, g23, g01, g23);
    unsigned w401 = pkhi(w4v[0], w4v[1]), w423 = pkhi(w4v[2], w4v[3]);
    unsigned wl01 = pkhi(w4v[0] - trunc_bf(w4v[0]), w4v[1] - trunc_bf(w4v[1]));
    unsigned wl23 = pkhi(w4v[2] - trunc_bf(w4v[2]), w4v[3] - trunc_bf(w4v[3]));
    bf16x8 Wf = mk8(w401, w423, wl01, wl23);
    asm("" : "+v"(Af), "+v"(Gf), "+v"(Wf));
    asm("" : "+v"(biasA), "+v"(biasG), "+v"(biasW));

    const f32x2* xb2 = reinterpret_cast<const f32x2*>(x + (size_t)b * NC * HW);
    f32x2*       ob2 = reinterpret_cast<f32x2*>(out + (size_t)b * NC * HW);
    int wib = ((bid & 255) << 2) + wave;
    unsigned basep = (unsigned)wib * 128 + (unsigned)m_;
    phase3<8>(xb2, ob2, basep, kg, Af, Gf, Wf, biasA, biasG, biasW);
}

// ---------------- cooperative fused kernel ----------------
__global__ __launch_bounds__(256) void k_fused(
    const float* __restrict__ x,
    const float* __restrict__ Wc, const float* __restrict__ bc,
    const float* __restrict__ W1, const float* __restrict__ b1,
    const float* __restrict__ W2, const float* __restrict__ b2,
    const float* __restrict__ W3, const float* __restrict__ b3,
    const float* __restrict__ W4, const float* __restrict__ b4,
    float* __restrict__ out, float* __restrict__ ws)
{
    int bid  = blockIdx.x;
    int b    = bid >> 7;            // batch
    int j    = bid & (BPB - 1);     // slice within batch
    int t    = threadIdx.x;
    int wave = t >> 6, lane = t & 63;

    float* psumB = ws;                        // [NB*NC*BPB]
    float* pmaxB = ws + NB * NC * BPB;        // [NB*NC*BPB]

    // phase 1: reduce own 2048-px slice
    {
        const float* xs = x + (size_t)b * NC * HW + (size_t)j * PXB;
        #pragma unroll
        for (int cc = 0; cc < 4; ++cc) {
            int c = wave * 4 + cc;
            const float4* p = reinterpret_cast<const float4*>(xs + (size_t)c * HW);
            float s = 0.0f, m = -INFINITY;
            #pragma unroll
            for (int it = 0; it < PXB / 256; ++it) {
                float4 v = p[it * 64 + lane];
                s += (v.x + v.y) + (v.z + v.w);
                m = fmaxf(m, fmaxf(fmaxf(v.x, v.y), fmaxf(v.z, v.w)));
            }
            #pragma unroll
            for (int off = 32; off > 0; off >>= 1) {
                s += __shfl_down(s, off, 64);
                m = fmaxf(m, __shfl_down(m, off, 64));
            }
            if (lane == 0) {
                psumB[(b * NC + c) * BPB + j] = s;
                pmaxB[(b * NC + c) * BPB + j] = m;
            }
        }
    }

    cg::this_grid().sync();

    // phase 2: per-block redundant fold
    __shared__ float lsum[NC][17], lmax[NC][17];
    __shared__ float r2s[NC], r4s[NC];
    {
        int c = t & 15, slot = t >> 4;
        const float* pb = psumB + (b * NC + c) * BPB;
        const float* mb = pmaxB + (b * NC + c) * BPB;
        float s = 0.0f, m = -INFINITY;
        #pragma unroll
        for (int k = 0; k < BPB / 16; ++k) {
            s += pb[slot * (BPB / 16) + k];
            m = fmaxf(m, mb[slot * (BPB / 16) + k]);
        }
        lsum[c][slot] = s; lmax[c][slot] = m;
    }
    __syncthreads();
    if (t < NC) {
        float ss = 0.0f, mm = -INFINITY;
        #pragma unroll
        for (int k = 0; k < 16; ++k) { ss += lsum[t][k]; mm = fmaxf(mm, lmax[t][k]); }
        r2s[t] = 1.0f / (ss * (1.0f / (float)HW) + EPS);
        r4s[t] = 1.0f / (mm + EPS);
    }
    __syncthreads();
    __shared__ float sA[NC][17], sG[NC][17], sbias[48];
    {
        int o = t >> 4, i = t & 15;
        float a = 0.0f, g = 0.0f;
        #pragma unroll
        for (int c = 0; c < NC; ++c) {
            a = fmaf(W2[o * 16 + c] * r2s[c], Wc[c * 16 + i], a);
            g = fmaf(W3[o * 16 + c] * r4s[c], W1[c * 16 + i], g);
        }
        sA[o][i] = a; sG[o][i] = g;
        if (t < NC) {
            float ba = 0.0f;
            #pragma unroll
            for (int c = 0; c < NC; ++c) ba = fmaf(W2[t * 16 + c] * r2s[c], bc[c], ba);
            sbias[t] = ba + b2[t];
        } else if (t < 2 * NC) {
            int o2 = t - NC; float bg = 0.0f;
            #pragma unroll
            for (int c = 0; c < NC; ++c) bg = fmaf(W3[o2 * 16 + c] * r4s[c], b1[c], bg);
            sbias[NC + o2] = bg + b3[o2];
        } else if (t < 3 * NC) {
            sbias[t] = b4[t - 2 * NC];
        }
    }
    __syncthreads();

    int m_ = lane & 15, kg = lane >> 4;
    f32x4 wa, wg, w4v, biasA, biasG, biasW;
    #pragma unroll
    for (int r = 0; r < 4; ++r) {
        wa[r]    = sA[m_][kg * 4 + r];
        wg[r]    = sG[m_][kg * 4 + r];
        w4v[r]   = W4[m_ * 16 + kg * 4 + r];
        biasA[r] = sbias[kg * 4 + r];
        biasG[r] = sbias[16 + kg * 4 + r];
        biasW[r] = sbias[32 + kg * 4 + r];
    }
    unsigned ah01 = pkhi(wa[0], wa[1]), ah23 = pkhi(wa[2], wa[3]);
    unsigned al01 = pkhi(wa[0] - trunc_bf(wa[0]), wa[1] - trunc_bf(wa[1]));
    unsigned al23 = pkhi(wa[2] - trunc_bf(wa[2]), wa[3] - trunc_bf(wa[3]));
    bf16x8 Af = mk8(ah01, ah23, al01, al23);
    unsigned g01 = pkhi(wg[0], wg[1]), g23 = pkhi(wg[2], wg[3]);
    bf16x8 Gf = mk8(g01, g23, g01, g23);
    unsigned w401 = pkhi(w4v[0], w4v[1]), w423 = pkhi(w4v[2], w4v[3]);
    unsigned wl01 = pkhi(w4v[0] - trunc_bf(w4v[0]), w4v[1] - trunc_bf(w4v[1]));
    unsigned wl23 = pkhi(w4v[2] - trunc_bf(w4v[2]), w4v[3] - trunc_bf(w4v[3]));
    bf16x8 Wf = mk8(w401, w423, wl01, wl23);
    asm("" : "+v"(Af), "+v"(Gf), "+v"(Wf));
    asm("" : "+v"(biasA), "+v"(biasG), "+v"(biasW));

    const f32x2* xb2 = reinterpret_cast<const f32x2*>(x + (size_t)b * NC * HW);
    f32x2*       ob2 = reinterpret_cast<f32x2*>(out + (size_t)b * NC * HW);
    unsigned basep = (unsigned)(j * (PXB / 2) + wave * (PXB / 8)) + (unsigned)m_;
    phase3<16>(xb2, ob2, basep, kg, Af, Gf, Wf, biasA, biasG, biasW);
}

extern "C" void kernel_launch(void* const* d_in, const int* in_sizes, int n_in,
                              void* d_out, int out_size, void* d_ws, size_t ws_size,
                              hipStream_t stream) {
    const float* x  = (const float*)d_in[0];
    const float* Wc = (const float*)d_in[1];
    const float* bc = (const float*)d_in[2];
    const float* W1 = (const float*)d_in[3];
    const float* b1 = (const float*)d_in[4];
    const float* W2 = (const float*)d_in[5];
    const float* b2 = (const float*)d_in[6];
    const float* W3 = (const float*)d_in[7];
    const float* b3 = (const float*)d_in[8];
    const float* W4 = (const float*)d_in[9];
    const float* b4 = (const float*)d_in[10];
    float* out = (float*)d_out;
    float* ws  = (float*)d_ws;

    // try cooperative fused kernel (gated; fall back on any failure)
    bool coop_done = false;
    if (ws_size >= (size_t)(2 * NB * NC * BPB) * sizeof(float)) {
        int dev = 0;
        (void)hipGetDevice(&dev);
        int coopAttr = 0, cus = 0, nbpc = 0;
        (void)hipDeviceGetAttribute(&coopAttr, hipDeviceAttributeCooperativeLaunch, dev);
        (void)hipDeviceGetAttribute(&cus, hipDeviceAttributeMultiprocessorCount, dev);
        hipError_t eo = hipOccupancyMaxActiveBlocksPerMultiprocessor(
            &nbpc, (const void*)k_fused, 256, 0);
        if (coopAttr && eo == hipSuccess && (long)nbpc * (long)cus >= (long)NBLK) {
            void* args[] = {(void*)&x, (void*)&Wc, (void*)&bc, (void*)&W1, (void*)&b1,
                            (void*)&W2, (void*)&b2, (void*)&W3, (void*)&b3,
                            (void*)&W4, (void*)&b4, (void*)&out, (void*)&ws};
            hipError_t e = hipLaunchCooperativeKernel((const void*)k_fused, dim3(NBLK),
                                                      dim3(256), args, 0, stream);
            if (e == hipSuccess) coop_done = true;
            else (void)hipGetLastError();   // clear sticky error, fall back
        }
    }
    if (coop_done) return;

    // fallback: 2-kernel path (same math)
    float* psum = ws;                        // [NB*NC*NSEG]
    float* pmax = psum + NB * NC * NSEG;     // [NB*NC*NSEG]
    k_reduce<<<NB * NC * NSEG, 256, 0, stream>>>(x, psum, pmax);
    k_main2<<<NB * 256, 256, 0, stream>>>(x, psum, pmax, Wc, bc, W1, b1,
                                          W2, b2, W3, b3, W4, b4, out);
}

// Round 13
// 67.273 us; speedup vs baseline: 1.0389x; 1.0389x over previous
//
#include <hip/hip_runtime.h>
#include <hip/hip_bf16.h>
#include <cmath>

#define HW   262144          // 512*512
#define NC   16
#define NB   8
#define NSEG 16
#define SEGSZ (HW / NSEG)    // 16384
#define EPS  1e-5f

typedef float f32x4 __attribute__((ext_vector_type(4)));
typedef float f32x2 __attribute__((ext_vector_type(2)));
typedef short bf16x8 __attribute__((ext_vector_type(8)));

// sigmoid(tanh(x)): tanh via fast exp+rcp, sigmoid via odd Taylor on [-1,1]
__device__ __forceinline__ float gsig(float x) {
    float E = __expf(2.0f * x);
    float t = 1.0f - 2.0f * __builtin_amdgcn_rcpf(E + 1.0f);   // tanh(x)
    float t2 = t * t;
    return fmaf(t, fmaf(t2, fmaf(t2, 0.0020833333f, -0.0208333333f), 0.25f), 0.5f);
}

static __device__ __forceinline__ bf16x8 mk8(unsigned a, unsigned b,
                                             unsigned c, unsigned d) {
    union { unsigned u[4]; bf16x8 v; } r;
    r.u[0] = a; r.u[1] = b; r.u[2] = c; r.u[3] = d;
    return r.v;
}
static __device__ __forceinline__ unsigned pkhi(float x0, float x1) {
    return (__float_as_uint(x0) >> 16) | (__float_as_uint(x1) & 0xFFFF0000u);
}
static __device__ __forceinline__ float trunc_bf(float x) {
    return __uint_as_float(__float_as_uint(x) & 0xFFFF0000u);
}

// one 16ch x 16px MFMA tile (split-bf16 for A and W4 paths)
static __device__ __forceinline__ f32x4 tile16(float x0, float x1, float x2, float x3,
                                               bf16x8 Af, bf16x8 Gf, bf16x8 Wf,
                                               f32x4 biasA, f32x4 biasG, f32x4 biasW) {
    unsigned vh01 = pkhi(x0, x1), vh23 = pkhi(x2, x3);
    unsigned vl01 = pkhi(x0 - trunc_bf(x0), x1 - trunc_bf(x1));
    unsigned vl23 = pkhi(x2 - trunc_bf(x2), x3 - trunc_bf(x3));
    bf16x8 B1 = mk8(vh01, vh23, vl01, vl23);   // [vh ; vl]
    bf16x8 B2 = mk8(vl01, vl23, vh01, vh23);   // [vl ; vh]
    f32x4 wh = __builtin_amdgcn_mfma_f32_16x16x32_bf16(Af, B1, biasA, 0, 0, 0);
    wh = __builtin_amdgcn_mfma_f32_16x16x32_bf16(Af, B2, wh, 0, 0, 0);
    f32x4 gr = __builtin_amdgcn_mfma_f32_16x16x32_bf16(Gf, B1, biasG, 0, 0, 0);
    float u0 = fmaf(x0, gsig(wh[0]) + gsig(gr[0]), x0);
    float u1 = fmaf(x1, gsig(wh[1]) + gsig(gr[1]), x1);
    float u2 = fmaf(x2, gsig(wh[2]) + gsig(gr[2]), x2);
    float u3 = fmaf(x3, gsig(wh[3]) + gsig(gr[3]), x3);
    unsigned uh01 = pkhi(u0, u1), uh23 = pkhi(u2, u3);
    unsigned ul01 = pkhi(u0 - trunc_bf(u0), u1 - trunc_bf(u1));
    unsigned ul23 = pkhi(u2 - trunc_bf(u2), u3 - trunc_bf(u3));
    f32x4 o = __builtin_amdgcn_mfma_f32_16x16x32_bf16(Wf, mk8(uh01, uh23, ul01, ul23), biasW, 0, 0, 0);
    o = __builtin_amdgcn_mfma_f32_16x16x32_bf16(Wf, mk8(ul01, ul23, uh01, uh23), o, 0, 0, 0);
    return o;
}

// ---------------- pass 1: per-(b,c,seg) partial sum & max ----------------
__global__ __launch_bounds__(256) void k_reduce(const float* __restrict__ x,
                                                float* __restrict__ psum,
                                                float* __restrict__ pmax) {
    int plane = blockIdx.x / NSEG;
    int seg   = blockIdx.x - plane * NSEG;
    const float4* p = reinterpret_cast<const float4*>(
        x + (size_t)plane * HW + (size_t)seg * SEGSZ);
    int t = threadIdx.x;
    float s = 0.0f, m = -INFINITY;
    #pragma unroll
    for (int it = 0; it < SEGSZ / (256 * 4); ++it) {
        float4 v = p[it * 256 + t];
        s += (v.x + v.y) + (v.z + v.w);
        m = fmaxf(m, fmaxf(fmaxf(v.x, v.y), fmaxf(v.z, v.w)));
    }
    #pragma unroll
    for (int off = 32; off > 0; off >>= 1) {
        s += __shfl_down(s, off, 64);
        m = fmaxf(m, __shfl_down(m, off, 64));
    }
    __shared__ float ls[4], lm[4];
    int wid = t >> 6, lane = t & 63;
    if (lane == 0) { ls[wid] = s; lm[wid] = m; }
    __syncthreads();
    if (t == 0) {
        psum[blockIdx.x] = (ls[0] + ls[1]) + (ls[2] + ls[3]);
        pmax[blockIdx.x] = fmaxf(fmaxf(lm[0], lm[1]), fmaxf(lm[2], lm[3]));
    }
}

// ---------------- pass 2: fold params in-block + MFMA main, 4 px/lane ----------------
__global__ __launch_bounds__(256) void k_main2(
    const float* __restrict__ x,
    const float* __restrict__ psum, const float* __restrict__ pmax,
    const float* __restrict__ Wc, const float* __restrict__ bc,
    const float* __restrict__ W1, const float* __restrict__ b1,
    const float* __restrict__ W2, const float* __restrict__ b2,
    const float* __restrict__ W3, const float* __restrict__ b3,
    const float* __restrict__ W4, const float* __restrict__ b4,
    float* __restrict__ out)
{
    int bid = blockIdx.x;
    int b   = bid >> 8;
    int t   = threadIdx.x;
    int wave = t >> 6, lane = t & 63;

    __shared__ float r2s[NC], r4s[NC];
    __shared__ float sA[NC][17], sG[NC][17], sbias[48];

    if (t < NC) {
        const float* src = psum + (b * NC + t) * NSEG;
        float s = 0.0f;
        #pragma unroll
        for (int k = 0; k < NSEG; ++k) s += src[k];
        r2s[t] = 1.0f / (s * (1.0f / (float)HW) + EPS);
    } else if (t < 2 * NC) {
        int c = t - NC;
        const float* src = pmax + (b * NC + c) * NSEG;
        float m = -INFINITY;
        #pragma unroll
        for (int k = 0; k < NSEG; ++k) m = fmaxf(m, src[k]);
        r4s[c] = 1.0f / (m + EPS);
    }
    __syncthreads();
    {
        int o = t >> 4, i = t & 15;
        float a = 0.0f, g = 0.0f;
        #pragma unroll
        for (int c = 0; c < NC; ++c) {
            a = fmaf(W2[o * 16 + c] * r2s[c], Wc[c * 16 + i], a);
            g = fmaf(W3[o * 16 + c] * r4s[c], W1[c * 16 + i], g);
        }
        sA[o][i] = a; sG[o][i] = g;
        if (t < NC) {
            float ba = 0.0f;
            #pragma unroll
            for (int c = 0; c < NC; ++c) ba = fmaf(W2[t * 16 + c] * r2s[c], bc[c], ba);
            sbias[t] = ba + b2[t];
        } else if (t < 2 * NC) {
            int o2 = t - NC; float bg = 0.0f;
            #pragma unroll
            for (int c = 0; c < NC; ++c) bg = fmaf(W3[o2 * 16 + c] * r4s[c], b1[c], bg);
            sbias[NC + o2] = bg + b3[o2];
        } else if (t < 3 * NC) {
            sbias[t] = b4[t - 2 * NC];
        }
    }
    __syncthreads();

    int m_ = lane & 15, kg = lane >> 4;
    f32x4 wa, wg, w4v, biasA, biasG, biasW;
    #pragma unroll
    for (int r = 0; r < 4; ++r) {
        wa[r]    = sA[m_][kg * 4 + r];
        wg[r]    = sG[m_][kg * 4 + r];
        w4v[r]   = W4[m_ * 16 + kg * 4 + r];
        biasA[r] = sbias[kg * 4 + r];
        biasG[r] = sbias[16 + kg * 4 + r];
        biasW[r] = sbias[32 + kg * 4 + r];
    }
    unsigned ah01 = pkhi(wa[0], wa[1]), ah23 = pkhi(wa[2], wa[3]);
    unsigned al01 = pkhi(wa[0] - trunc_bf(wa[0]), wa[1] - trunc_bf(wa[1]));
    unsigned al23 = pkhi(wa[2] - trunc_bf(wa[2]), wa[3] - trunc_bf(wa[3]));
    bf16x8 Af = mk8(ah01, ah23, al01, al23);
    unsigned g01 = pkhi(wg[0], wg[1]), g23 = pkhi(wg[2], wg[3]);
    bf16x8 Gf = mk8(g01, g23, g01, g23);
    unsigned w401 = pkhi(w4v[0], w4v[1]), w423 = pkhi(w4v[2], w4v[3]);
    unsigned wl01 = pkhi(w4v[0] - trunc_bf(w4v[0]), w4v[1] - trunc_bf(w4v[1]));
    unsigned wl23 = pkhi(w4v[2] - trunc_bf(w4v[2]), w4v[3] - trunc_bf(w4v[3]));
    bf16x8 Wf = mk8(w401, w423, wl01, wl23);
    asm("" : "+v"(Af), "+v"(Gf), "+v"(Wf));
    asm("" : "+v"(biasA), "+v"(biasG), "+v"(biasW));

    // phase 3: 4 px/lane (f32x4), 4 independent tile chains, dwordx4 loads/stores
    const f32x4* xb4 = reinterpret_cast<const f32x4*>(x + (size_t)b * NC * HW);
    f32x4*       ob4 = reinterpret_cast<f32x4*>(out + (size_t)b * NC * HW);
    int wib = ((bid & 255) << 2) + wave;           // wave in batch [0,1024)
    unsigned basep = (unsigned)wib * 64 + (unsigned)m_;   // f32x4 units
    unsigned off0 = (unsigned)(kg * 4 + 0) * (HW / 4) + basep;
    unsigned off1 = (unsigned)(kg * 4 + 1) * (HW / 4) + basep;
    unsigned off2 = (unsigned)(kg * 4 + 2) * (HW / 4) + basep;
    unsigned off3 = (unsigned)(kg * 4 + 3) * (HW / 4) + basep;

    #pragma unroll
    for (int it = 0; it < 4; ++it) {
        f32x4 v0 = xb4[off0 + it * 16];
        f32x4 v1 = xb4[off1 + it * 16];
        f32x4 v2 = xb4[off2 + it * 16];
        f32x4 v3 = xb4[off3 + it * 16];

        f32x4 oA = tile16(v0[0], v1[0], v2[0], v3[0], Af, Gf, Wf, biasA, biasG, biasW);
        f32x4 oB = tile16(v0[1], v1[1], v2[1], v3[1], Af, Gf, Wf, biasA, biasG, biasW);
        f32x4 oC = tile16(v0[2], v1[2], v2[2], v3[2], Af, Gf, Wf, biasA, biasG, biasW);
        f32x4 oD = tile16(v0[3], v1[3], v2[3], v3[3], Af, Gf, Wf, biasA, biasG, biasW);

        f32x4 s0; s0[0] = oA[0]; s0[1] = oB[0]; s0[2] = oC[0]; s0[3] = oD[0];
        f32x4 s1; s1[0] = oA[1]; s1[1] = oB[1]; s1[2] = oC[1]; s1[3] = oD[1];
        f32x4 s2; s2[0] = oA[2]; s2[1] = oB[2]; s2[2] = oC[2]; s2[3] = oD[2];
        f32x4 s3; s3[0] = oA[3]; s3[1] = oB[3]; s3[2] = oC[3]; s3[3] = oD[3];
        __builtin_nontemporal_store(s0, &ob4[off0 + it * 16]);
        __builtin_nontemporal_store(s1, &ob4[off1 + it * 16]);
        __builtin_nontemporal_store(s2, &ob4[off2 + it * 16]);
        __builtin_nontemporal_store(s3, &ob4[off3 + it * 16]);
    }
}

extern "C" void kernel_launch(void* const* d_in, const int* in_sizes, int n_in,
                              void* d_out, int out_size, void* d_ws, size_t ws_size,
                              hipStream_t stream) {
    const float* x  = (const float*)d_in[0];
    const float* Wc = (const float*)d_in[1];
    const float* bc = (const float*)d_in[2];
    const float* W1 = (const float*)d_in[3];
    const float* b1 = (const float*)d_in[4];
    const float* W2 = (const float*)d_in[5];
    const float* b2 = (const float*)d_in[6];
    const float* W3 = (const float*)d_in[7];
    const float* b3 = (const float*)d_in[8];
    const float* W4 = (const float*)d_in[9];
    const float* b4 = (const float*)d_in[10];
    float* out = (float*)d_out;

    float* psum = (float*)d_ws;              // [NB*NC*NSEG]
    float* pmax = psum + NB * NC * NSEG;     // [NB*NC*NSEG]

    k_reduce<<<NB * NC * NSEG, 256, 0, stream>>>(x, psum, pmax);
    k_main2<<<NB * 256, 256, 0, stream>>>(x, psum, pmax, Wc, bc, W1, b1,
                                          W2, b2, W3, b3, W4, b4, out);
}